// Round 5
// baseline (1301.372 us; speedup 1.0000x reference)
//
#include <hip/hip_runtime.h>
#include <hip/hip_bf16.h>

#define N_USERS 80000
#define N_ITEMS 30000
#define N_TOTAL 110000
#define DD 64
#define NNZ_ADJ 2000000
#define NNZ_MM 300000

typedef __hip_bfloat16 bf16;

// ---------------- diagnostic sentinel ---------------------------------------

__global__ void k_sentinel(float* out, float v)
{
    if (threadIdx.x == 0 && blockIdx.x == 0) out[0] = v;
}

// ---------------- SpMM: one wave per nnz, lane = dim ------------------------

__global__ void k_spmm(const int* __restrict__ rows, const int* __restrict__ cols,
                       const float* __restrict__ vals, const float* __restrict__ x,
                       float* __restrict__ out, int nnz, int nrows, int ncols)
{
    const int lane = threadIdx.x & 63;
    int wave       = blockIdx.x * (blockDim.x >> 6) + (threadIdx.x >> 6);
    const int nwav = gridDim.x * (blockDim.x >> 6);
    for (int n = wave; n < nnz; n += nwav) {
        const int r = rows[n];
        const int c = cols[n];
        if ((unsigned)r >= (unsigned)nrows || (unsigned)c >= (unsigned)ncols) continue;
        const float v  = vals[n];
        const float xv = x[(size_t)c * DD + lane];
        atomicAdd(out + (size_t)r * DD + lane, v * xv);
    }
}

__global__ void k_spmm_ego(const int* __restrict__ rows, const int* __restrict__ cols,
                           const float* __restrict__ vals,
                           const float* __restrict__ ue, const float* __restrict__ ie,
                           float* __restrict__ out, int nnz)
{
    const int lane = threadIdx.x & 63;
    int wave       = blockIdx.x * (blockDim.x >> 6) + (threadIdx.x >> 6);
    const int nwav = gridDim.x * (blockDim.x >> 6);
    for (int n = wave; n < nnz; n += nwav) {
        const int r = rows[n];
        const int c = cols[n];
        if ((unsigned)r >= (unsigned)N_TOTAL || (unsigned)c >= (unsigned)N_TOTAL) continue;
        const float v  = vals[n];
        const float xv = (c < N_USERS) ? ue[(size_t)c * DD + lane]
                                       : ie[(size_t)(c - N_USERS) * DD + lane];
        atomicAdd(out + (size_t)r * DD + lane, v * xv);
    }
}

// -------- fused modality attention: w = softmax(q(img),q(txt)); h = blend ----

__global__ __launch_bounds__(256) void k_mm_fuse(
    const float* __restrict__ img_e, const float* __restrict__ txt_e,
    const float* __restrict__ Wq1, const float* __restrict__ bq1, const float* __restrict__ wq2,
    float* __restrict__ h_ws,
    float* __restrict__ out_img, float* __restrict__ out_txt, float* __restrict__ out_h)
{
    __shared__ float sW[DD * DD];
    __shared__ float sb[DD];
    __shared__ float sq[DD];
    for (int i = threadIdx.x; i < DD * DD; i += blockDim.x) sW[i] = Wq1[i];
    if (threadIdx.x < DD) {
        sb[threadIdx.x] = bq1[threadIdx.x];
        sq[threadIdx.x] = wq2[threadIdx.x];
    }
    __syncthreads();

    const int lane = threadIdx.x & 63;
    int wave       = blockIdx.x * (blockDim.x >> 6) + (threadIdx.x >> 6);
    const int nwav = gridDim.x * (blockDim.x >> 6);

    for (int i = wave; i < N_ITEMS; i += nwav) {
        const size_t base = (size_t)i * DD + lane;
        const float iv = img_e[base];
        const float tv = txt_e[base];
        // hidden_j = tanh(b_j + sum_k x_k W[k][j]); lane = j
        float ai = sb[lane], at = sb[lane];
        #pragma unroll 8
        for (int k = 0; k < DD; ++k) {
            const float w = sW[k * DD + lane];
            ai += __shfl(iv, k) * w;
            at += __shfl(tv, k) * w;
        }
        float si = tanhf(ai) * sq[lane];
        float st = tanhf(at) * sq[lane];
        #pragma unroll
        for (int off = 32; off; off >>= 1) {
            si += __shfl_xor(si, off);
            st += __shfl_xor(st, off);
        }
        const float m  = fmaxf(si, st);
        const float ei = expf(si - m), et = expf(st - m);
        const float w0 = ei / (ei + et);
        const float w1 = et / (ei + et);
        const float h  = w0 * iv + w1 * tv;
        h_ws[base]    = h;
        out_img[base] = iv;
        out_txt[base] = tv;
        out_h[base]   = h;
    }
}

// ---- final item path: i_g0, h_norm, cross-attention blend -> i_g -----------

__global__ __launch_bounds__(256) void k_item_final(
    const float* __restrict__ ie, const float* __restrict__ cur1, const float* __restrict__ cur2,
    const float* __restrict__ h_ws,
    const float* __restrict__ Wc1, const float* __restrict__ bc1, const float* __restrict__ wc2,
    float* __restrict__ out_ig)
{
    __shared__ float sW[DD * DD];
    __shared__ float sb[DD];
    __shared__ float sq[DD];
    for (int i = threadIdx.x; i < DD * DD; i += blockDim.x) sW[i] = Wc1[i];
    if (threadIdx.x < DD) {
        sb[threadIdx.x] = bc1[threadIdx.x];
        sq[threadIdx.x] = wc2[threadIdx.x];
    }
    __syncthreads();

    const int lane = threadIdx.x & 63;
    int wave       = blockIdx.x * (blockDim.x >> 6) + (threadIdx.x >> 6);
    const int nwav = gridDim.x * (blockDim.x >> 6);

    for (int i = wave; i < N_ITEMS; i += nwav) {
        const size_t base  = (size_t)i * DD + lane;
        const size_t gbase = (size_t)(N_USERS + i) * DD + lane;
        const float ig = (ie[base] + cur1[gbase] + cur2[gbase]) * (1.0f / 3.0f);
        const float hv = h_ws[base];
        float ss = hv * hv;
        #pragma unroll
        for (int off = 32; off; off >>= 1) ss += __shfl_xor(ss, off);
        const float hn = hv / fmaxf(sqrtf(ss), 1e-12f);

        float a0 = sb[lane], a1 = sb[lane];
        #pragma unroll 8
        for (int k = 0; k < DD; ++k) {
            const float w = sW[k * DD + lane];
            a0 += __shfl(ig, k) * w;
            a1 += __shfl(hn, k) * w;
        }
        float s0 = tanhf(a0) * sq[lane];
        float s1 = tanhf(a1) * sq[lane];
        #pragma unroll
        for (int off = 32; off; off >>= 1) {
            s0 += __shfl_xor(s0, off);
            s1 += __shfl_xor(s1, off);
        }
        const float m  = fmaxf(s0, s1);
        const float e0 = expf(s0 - m), e1 = expf(s1 - m);
        const float w0 = e0 / (e0 + e1);
        const float w1 = e1 / (e0 + e1);
        out_ig[base] = w0 * ig + w1 * hn;
    }
}

// ------------------------ final user path (elementwise) ---------------------

__global__ void k_user_final(const float* __restrict__ ue, const float* __restrict__ cur1,
                             const float* __restrict__ cur2, float* __restrict__ out)
{
    const size_t n = (size_t)N_USERS * DD;
    for (size_t idx = (size_t)blockIdx.x * blockDim.x + threadIdx.x; idx < n;
         idx += (size_t)gridDim.x * blockDim.x) {
        out[idx] = (ue[idx] + cur1[idx] + cur2[idx]) * (1.0f / 3.0f);
    }
}

// ----------------------------------------------------------------------------

extern "C" void kernel_launch(void* const* d_in, const int* in_sizes, int n_in,
                              void* d_out, int out_size, void* d_ws, size_t ws_size,
                              hipStream_t stream)
{
    static const int EXP[17] = {
        N_USERS * DD, N_ITEMS * DD, DD * DD, DD, DD, DD * DD, DD, DD,
        NNZ_ADJ, NNZ_MM, NNZ_MM, NNZ_ADJ, NNZ_ADJ, NNZ_MM, NNZ_MM, NNZ_MM, NNZ_MM
    };
    const size_t WS_NEED = (size_t)((size_t)N_ITEMS * DD * 2 +
                                    (size_t)N_TOTAL * DD * 2 +
                                    (size_t)N_ITEMS * DD) * sizeof(float);

    float* out = (float*)d_out;

    if (ws_size < WS_NEED) {
        k_sentinel<<<1, 64, 0, stream>>>(out, 3000.0f + (float)(ws_size >> 20));
        return;
    }
    const int OUT_EXPECT = (N_USERS + 4 * N_ITEMS) * DD; // 12,800,000
    if (out_size != OUT_EXPECT) {
        k_sentinel<<<1, 64, 0, stream>>>(out, 5000.0f + (float)(((unsigned)out_size) >> 20));
        return;
    }
    if (n_in < 17) {
        k_sentinel<<<1, 64, 0, stream>>>(out, 1000.0f + 8.0f * (float)n_in);
        return;
    }

    int map[17];
    bool exact = true;
    for (int i = 0; i < 17; ++i) { map[i] = i; if (in_sizes[i] != EXP[i]) exact = false; }
    if (!exact) {
        bool used[64] = {false};
        for (int i = 0; i < 17; ++i) {
            int found = -1;
            for (int j = 0; j < n_in && j < 64; ++j)
                if (!used[j] && in_sizes[j] == EXP[i]) { found = j; break; }
            if (found < 0) {
                k_sentinel<<<1, 64, 0, stream>>>(out, 2000.0f + 32.0f * (float)i);
                return;
            }
            used[found] = true; map[i] = found;
        }
    }

    const float* user_emb = (const float*)d_in[map[0]];
    const float* item_emb = (const float*)d_in[map[1]];
    const float* Wq1      = (const float*)d_in[map[2]];
    const float* bq1      = (const float*)d_in[map[3]];
    const float* wq2      = (const float*)d_in[map[4]];
    const float* Wc1      = (const float*)d_in[map[5]];
    const float* bc1      = (const float*)d_in[map[6]];
    const float* wc2      = (const float*)d_in[map[7]];
    const float* adj_vals = (const float*)d_in[map[8]];
    const float* img_vals = (const float*)d_in[map[9]];
    const float* txt_vals = (const float*)d_in[map[10]];
    const int* adj_rows   = (const int*)d_in[map[11]];
    const int* adj_cols   = (const int*)d_in[map[12]];
    const int* img_rows   = (const int*)d_in[map[13]];
    const int* img_cols   = (const int*)d_in[map[14]];
    const int* txt_rows   = (const int*)d_in[map[15]];
    const int* txt_cols   = (const int*)d_in[map[16]];

    float* ws    = (float*)d_ws;
    float* img_e = ws;                                 // N_ITEMS*DD
    float* txt_e = img_e + (size_t)N_ITEMS * DD;       // N_ITEMS*DD
    float* cur1  = txt_e + (size_t)N_ITEMS * DD;       // N_TOTAL*DD
    float* cur2  = cur1  + (size_t)N_TOTAL * DD;       // N_TOTAL*DD
    float* h_ws  = cur2  + (size_t)N_TOTAL * DD;       // N_ITEMS*DD (fully written)

    const size_t zero_floats = (size_t)N_ITEMS * DD * 2 + (size_t)N_TOTAL * DD * 2;
    hipMemsetAsync(d_ws, 0, zero_floats * sizeof(float), stream);

    float* out_ug  = out;
    float* out_ig  = out_ug  + (size_t)N_USERS * DD;
    float* out_img = out_ig  + (size_t)N_ITEMS * DD;
    float* out_txt = out_img + (size_t)N_ITEMS * DD;
    float* out_h   = out_txt + (size_t)N_ITEMS * DD;

    // modality SpMMs (independent)
    k_spmm<<<1024, 256, 0, stream>>>(img_rows, img_cols, img_vals, item_emb,
                                     img_e, NNZ_MM, N_ITEMS, N_ITEMS);
    k_spmm<<<1024, 256, 0, stream>>>(txt_rows, txt_cols, txt_vals, item_emb,
                                     txt_e, NNZ_MM, N_ITEMS, N_ITEMS);

    // UI graph propagation: cur1 = A*ego ; cur2 = A*cur1
    k_spmm_ego<<<4096, 256, 0, stream>>>(adj_rows, adj_cols, adj_vals,
                                         user_emb, item_emb, cur1, NNZ_ADJ);
    k_spmm<<<4096, 256, 0, stream>>>(adj_rows, adj_cols, adj_vals, cur1,
                                     cur2, NNZ_ADJ, N_TOTAL, N_TOTAL);

    // modality attention + h
    k_mm_fuse<<<512, 256, 0, stream>>>(img_e, txt_e, Wq1, bq1, wq2,
                                       h_ws, out_img, out_txt, out_h);

    // final outputs
    k_user_final<<<4096, 256, 0, stream>>>(user_emb, cur1, cur2, out_ug);
    k_item_final<<<512, 256, 0, stream>>>(item_emb, cur1, cur2, h_ws,
                                          Wc1, bc1, wc2, out_ig);
}

// Round 6
// 933.330 us; speedup vs baseline: 1.3943x; 1.3943x over previous
//
#include <hip/hip_runtime.h>
#include <hip/hip_bf16.h>

#define N_USERS 80000
#define N_ITEMS 30000
#define N_TOTAL 110000
#define DD 64
#define NNZ_ADJ 2000000
#define NNZ_MM 300000

// ---------------- diagnostic sentinel ---------------------------------------

__global__ void k_sentinel(float* out, float v)
{
    if (threadIdx.x == 0 && blockIdx.x == 0) out[0] = v;
}

// ======================= CSR construction ===================================

__global__ void k_count(const int* __restrict__ rows, int* __restrict__ cnt,
                        int nnz, int nrows)
{
    for (int i = blockIdx.x * blockDim.x + threadIdx.x; i < nnz;
         i += gridDim.x * blockDim.x) {
        const int r = rows[i];
        if ((unsigned)r < (unsigned)nrows) atomicAdd(&cnt[r], 1);
    }
}

struct ScanArg { int* cnt; int* rp; int* off; int n; };

// 3 blocks, one per matrix: hierarchical exclusive scan, 4096 elems/iter
__global__ __launch_bounds__(1024) void k_scan(ScanArg a0, ScanArg a1, ScanArg a2)
{
    ScanArg A = (blockIdx.x == 0) ? a0 : (blockIdx.x == 1) ? a1 : a2;
    __shared__ int swav[16];
    __shared__ int carry;
    const int lane = threadIdx.x & 63;
    const int wid  = threadIdx.x >> 6;
    if (threadIdx.x == 0) carry = 0;
    __syncthreads();

    for (int base = 0; base < A.n; base += 4096) {
        const int i0 = base + threadIdx.x * 4;
        int v0 = (i0 + 0 < A.n) ? A.cnt[i0 + 0] : 0;
        int v1 = (i0 + 1 < A.n) ? A.cnt[i0 + 1] : 0;
        int v2 = (i0 + 2 < A.n) ? A.cnt[i0 + 2] : 0;
        int v3 = (i0 + 3 < A.n) ? A.cnt[i0 + 3] : 0;
        const int tsum = v0 + v1 + v2 + v3;

        // wave inclusive scan of tsum
        int x = tsum;
        #pragma unroll
        for (int o = 1; o < 64; o <<= 1) {
            int t = __shfl_up(x, o);
            if (lane >= o) x += t;
        }
        if (lane == 63) swav[wid] = x;
        __syncthreads();
        if (wid == 0) {
            int y = (lane < 16) ? swav[lane] : 0;
            #pragma unroll
            for (int o = 1; o < 16; o <<= 1) {
                int t = __shfl_up(y, o);
                if (lane >= o) y += t;
            }
            if (lane < 16) swav[lane] = y;
        }
        __syncthreads();
        const int wbase  = (wid > 0) ? swav[wid - 1] : 0;
        int e = carry + wbase + (x - tsum);   // exclusive prefix at i0
        if (i0 + 0 < A.n) { A.rp[i0 + 0] = e; A.off[i0 + 0] = e; } e += v0;
        if (i0 + 1 < A.n) { A.rp[i0 + 1] = e; A.off[i0 + 1] = e; } e += v1;
        if (i0 + 2 < A.n) { A.rp[i0 + 2] = e; A.off[i0 + 2] = e; } e += v2;
        if (i0 + 3 < A.n) { A.rp[i0 + 3] = e; A.off[i0 + 3] = e; }
        const int tot = swav[15];
        __syncthreads();
        if (threadIdx.x == 0) carry += tot;
        __syncthreads();
    }
    if (threadIdx.x == 0) A.rp[A.n] = carry;
}

__global__ void k_scatter(const int* __restrict__ rows, const int* __restrict__ cols,
                          const float* __restrict__ vals, int* __restrict__ off,
                          int* __restrict__ ecol, float* __restrict__ eval,
                          int nnz, int nrows, int ncols)
{
    for (int i = blockIdx.x * blockDim.x + threadIdx.x; i < nnz;
         i += gridDim.x * blockDim.x) {
        const int r = rows[i];
        const int c = cols[i];
        if ((unsigned)r >= (unsigned)nrows || (unsigned)c >= (unsigned)ncols) continue;
        const int pos = atomicAdd(&off[r], 1);
        ecol[pos] = c;
        eval[pos] = vals[i];
    }
}

// ======================= CSR SpMM: wave per row, lane = dim =================

__global__ __launch_bounds__(256) void k_spmm_csr(
    const int* __restrict__ rp, const int* __restrict__ ecol,
    const float* __restrict__ eval, const float* __restrict__ x,
    float* __restrict__ out, int nrows)
{
    const int lane = threadIdx.x & 63;
    int wave       = blockIdx.x * (blockDim.x >> 6) + (threadIdx.x >> 6);
    const int nwav = gridDim.x * (blockDim.x >> 6);
    for (int r = wave; r < nrows; r += nwav) {
        const int j0 = rp[r], j1 = rp[r + 1];
        float acc = 0.f;
        for (int j = j0; j < j1; j += 64) {
            const int cnt = min(64, j1 - j);
            int c = 0; float v = 0.f;
            if (lane < cnt) { c = ecol[j + lane]; v = eval[j + lane]; }
            for (int k = 0; k < cnt; ++k) {
                const int   ck = __shfl(c, k);
                const float vk = __shfl(v, k);
                acc += vk * x[(size_t)ck * DD + lane];
            }
        }
        out[(size_t)r * DD + lane] = acc;
    }
}

__global__ __launch_bounds__(256) void k_spmm_csr_ego(
    const int* __restrict__ rp, const int* __restrict__ ecol,
    const float* __restrict__ eval,
    const float* __restrict__ ue, const float* __restrict__ ie,
    float* __restrict__ out, int nrows)
{
    const int lane = threadIdx.x & 63;
    int wave       = blockIdx.x * (blockDim.x >> 6) + (threadIdx.x >> 6);
    const int nwav = gridDim.x * (blockDim.x >> 6);
    for (int r = wave; r < nrows; r += nwav) {
        const int j0 = rp[r], j1 = rp[r + 1];
        float acc = 0.f;
        for (int j = j0; j < j1; j += 64) {
            const int cnt = min(64, j1 - j);
            int c = 0; float v = 0.f;
            if (lane < cnt) { c = ecol[j + lane]; v = eval[j + lane]; }
            for (int k = 0; k < cnt; ++k) {
                const int   ck = __shfl(c, k);
                const float vk = __shfl(v, k);
                const float xv = (ck < N_USERS)
                               ? ue[(size_t)ck * DD + lane]
                               : ie[(size_t)(ck - N_USERS) * DD + lane];
                acc += vk * xv;
            }
        }
        out[(size_t)r * DD + lane] = acc;
    }
}

// ---------------- fallback atomic SpMM (used only if ws too small) ----------

__global__ void k_spmm_at(const int* __restrict__ rows, const int* __restrict__ cols,
                          const float* __restrict__ vals, const float* __restrict__ x,
                          float* __restrict__ out, int nnz, int nrows, int ncols)
{
    const int lane = threadIdx.x & 63;
    int wave       = blockIdx.x * (blockDim.x >> 6) + (threadIdx.x >> 6);
    const int nwav = gridDim.x * (blockDim.x >> 6);
    for (int n = wave; n < nnz; n += nwav) {
        const int r = rows[n];
        const int c = cols[n];
        if ((unsigned)r >= (unsigned)nrows || (unsigned)c >= (unsigned)ncols) continue;
        atomicAdd(out + (size_t)r * DD + lane, vals[n] * x[(size_t)c * DD + lane]);
    }
}

__global__ void k_spmm_at_ego(const int* __restrict__ rows, const int* __restrict__ cols,
                              const float* __restrict__ vals,
                              const float* __restrict__ ue, const float* __restrict__ ie,
                              float* __restrict__ out, int nnz)
{
    const int lane = threadIdx.x & 63;
    int wave       = blockIdx.x * (blockDim.x >> 6) + (threadIdx.x >> 6);
    const int nwav = gridDim.x * (blockDim.x >> 6);
    for (int n = wave; n < nnz; n += nwav) {
        const int r = rows[n];
        const int c = cols[n];
        if ((unsigned)r >= (unsigned)N_TOTAL || (unsigned)c >= (unsigned)N_TOTAL) continue;
        const float xv = (c < N_USERS) ? ue[(size_t)c * DD + lane]
                                       : ie[(size_t)(c - N_USERS) * DD + lane];
        atomicAdd(out + (size_t)r * DD + lane, vals[n] * xv);
    }
}

// -------- fused modality attention: w = softmax(q(img),q(txt)); h = blend ----

__global__ __launch_bounds__(256) void k_mm_fuse(
    const float* __restrict__ img_e, const float* __restrict__ txt_e,
    const float* __restrict__ Wq1, const float* __restrict__ bq1, const float* __restrict__ wq2,
    float* __restrict__ h_ws,
    float* __restrict__ out_img, float* __restrict__ out_txt, float* __restrict__ out_h)
{
    __shared__ float sW[DD * DD];
    __shared__ float sb[DD];
    __shared__ float sq[DD];
    for (int i = threadIdx.x; i < DD * DD; i += blockDim.x) sW[i] = Wq1[i];
    if (threadIdx.x < DD) {
        sb[threadIdx.x] = bq1[threadIdx.x];
        sq[threadIdx.x] = wq2[threadIdx.x];
    }
    __syncthreads();

    const int lane = threadIdx.x & 63;
    int wave       = blockIdx.x * (blockDim.x >> 6) + (threadIdx.x >> 6);
    const int nwav = gridDim.x * (blockDim.x >> 6);

    for (int i = wave; i < N_ITEMS; i += nwav) {
        const size_t base = (size_t)i * DD + lane;
        const float iv = img_e[base];
        const float tv = txt_e[base];
        float ai = sb[lane], at = sb[lane];
        #pragma unroll 8
        for (int k = 0; k < DD; ++k) {
            const float w = sW[k * DD + lane];
            ai += __shfl(iv, k) * w;
            at += __shfl(tv, k) * w;
        }
        float si = tanhf(ai) * sq[lane];
        float st = tanhf(at) * sq[lane];
        #pragma unroll
        for (int off = 32; off; off >>= 1) {
            si += __shfl_xor(si, off);
            st += __shfl_xor(st, off);
        }
        const float m  = fmaxf(si, st);
        const float ei = expf(si - m), et = expf(st - m);
        const float w0 = ei / (ei + et);
        const float w1 = et / (ei + et);
        const float h  = w0 * iv + w1 * tv;
        h_ws[base]    = h;
        out_img[base] = iv;
        out_txt[base] = tv;
        out_h[base]   = h;
    }
}

// ---- final item path: i_g0, h_norm, cross-attention blend -> i_g -----------

__global__ __launch_bounds__(256) void k_item_final(
    const float* __restrict__ ie, const float* __restrict__ cur1, const float* __restrict__ cur2,
    const float* __restrict__ h_ws,
    const float* __restrict__ Wc1, const float* __restrict__ bc1, const float* __restrict__ wc2,
    float* __restrict__ out_ig)
{
    __shared__ float sW[DD * DD];
    __shared__ float sb[DD];
    __shared__ float sq[DD];
    for (int i = threadIdx.x; i < DD * DD; i += blockDim.x) sW[i] = Wc1[i];
    if (threadIdx.x < DD) {
        sb[threadIdx.x] = bc1[threadIdx.x];
        sq[threadIdx.x] = wc2[threadIdx.x];
    }
    __syncthreads();

    const int lane = threadIdx.x & 63;
    int wave       = blockIdx.x * (blockDim.x >> 6) + (threadIdx.x >> 6);
    const int nwav = gridDim.x * (blockDim.x >> 6);

    for (int i = wave; i < N_ITEMS; i += nwav) {
        const size_t base  = (size_t)i * DD + lane;
        const size_t gbase = (size_t)(N_USERS + i) * DD + lane;
        const float ig = (ie[base] + cur1[gbase] + cur2[gbase]) * (1.0f / 3.0f);
        const float hv = h_ws[base];
        float ss = hv * hv;
        #pragma unroll
        for (int off = 32; off; off >>= 1) ss += __shfl_xor(ss, off);
        const float hn = hv / fmaxf(sqrtf(ss), 1e-12f);

        float a0 = sb[lane], a1 = sb[lane];
        #pragma unroll 8
        for (int k = 0; k < DD; ++k) {
            const float w = sW[k * DD + lane];
            a0 += __shfl(ig, k) * w;
            a1 += __shfl(hn, k) * w;
        }
        float s0 = tanhf(a0) * sq[lane];
        float s1 = tanhf(a1) * sq[lane];
        #pragma unroll
        for (int off = 32; off; off >>= 1) {
            s0 += __shfl_xor(s0, off);
            s1 += __shfl_xor(s1, off);
        }
        const float m  = fmaxf(s0, s1);
        const float e0 = expf(s0 - m), e1 = expf(s1 - m);
        const float w0 = e0 / (e0 + e1);
        const float w1 = e1 / (e0 + e1);
        out_ig[base] = w0 * ig + w1 * hn;
    }
}

// ------------------------ final user path (elementwise) ---------------------

__global__ void k_user_final(const float* __restrict__ ue, const float* __restrict__ cur1,
                             const float* __restrict__ cur2, float* __restrict__ out)
{
    const size_t n = (size_t)N_USERS * DD;
    for (size_t idx = (size_t)blockIdx.x * blockDim.x + threadIdx.x; idx < n;
         idx += (size_t)gridDim.x * blockDim.x) {
        out[idx] = (ue[idx] + cur1[idx] + cur2[idx]) * (1.0f / 3.0f);
    }
}

// ----------------------------------------------------------------------------

extern "C" void kernel_launch(void* const* d_in, const int* in_sizes, int n_in,
                              void* d_out, int out_size, void* d_ws, size_t ws_size,
                              hipStream_t stream)
{
    static const int EXP[17] = {
        N_USERS * DD, N_ITEMS * DD, DD * DD, DD, DD, DD * DD, DD, DD,
        NNZ_ADJ, NNZ_MM, NNZ_MM, NNZ_ADJ, NNZ_ADJ, NNZ_MM, NNZ_MM, NNZ_MM, NNZ_MM
    };

    float* out = (float*)d_out;

    const int OUT_EXPECT = (N_USERS + 4 * N_ITEMS) * DD;
    if (out_size != OUT_EXPECT) {
        k_sentinel<<<1, 64, 0, stream>>>(out, 5000.0f + (float)(((unsigned)out_size) >> 20));
        return;
    }
    if (n_in < 17) {
        k_sentinel<<<1, 64, 0, stream>>>(out, 1000.0f + 8.0f * (float)n_in);
        return;
    }

    int map[17];
    bool exact = true;
    for (int i = 0; i < 17; ++i) { map[i] = i; if (in_sizes[i] != EXP[i]) exact = false; }
    if (!exact) {
        bool used[64] = {false};
        for (int i = 0; i < 17; ++i) {
            int found = -1;
            for (int j = 0; j < n_in && j < 64; ++j)
                if (!used[j] && in_sizes[j] == EXP[i]) { found = j; break; }
            if (found < 0) {
                k_sentinel<<<1, 64, 0, stream>>>(out, 2000.0f + 32.0f * (float)i);
                return;
            }
            used[found] = true; map[i] = found;
        }
    }

    const float* user_emb = (const float*)d_in[map[0]];
    const float* item_emb = (const float*)d_in[map[1]];
    const float* Wq1      = (const float*)d_in[map[2]];
    const float* bq1      = (const float*)d_in[map[3]];
    const float* wq2      = (const float*)d_in[map[4]];
    const float* Wc1      = (const float*)d_in[map[5]];
    const float* bc1      = (const float*)d_in[map[6]];
    const float* wc2      = (const float*)d_in[map[7]];
    const float* adj_vals = (const float*)d_in[map[8]];
    const float* img_vals = (const float*)d_in[map[9]];
    const float* txt_vals = (const float*)d_in[map[10]];
    const int* adj_rows   = (const int*)d_in[map[11]];
    const int* adj_cols   = (const int*)d_in[map[12]];
    const int* img_rows   = (const int*)d_in[map[13]];
    const int* img_cols   = (const int*)d_in[map[14]];
    const int* txt_rows   = (const int*)d_in[map[15]];
    const int* txt_cols   = (const int*)d_in[map[16]];

    // -------- float workspace layout --------
    float* ws    = (float*)d_ws;
    float* img_e = ws;
    float* txt_e = img_e + (size_t)N_ITEMS * DD;
    float* cur1  = txt_e + (size_t)N_ITEMS * DD;
    float* cur2  = cur1  + (size_t)N_TOTAL * DD;
    float* h_ws  = cur2  + (size_t)N_TOTAL * DD;
    float* f_end = h_ws  + (size_t)N_ITEMS * DD;

    float* out_ug  = out;
    float* out_ig  = out_ug  + (size_t)N_USERS * DD;
    float* out_img = out_ig  + (size_t)N_ITEMS * DD;
    float* out_txt = out_img + (size_t)N_ITEMS * DD;
    float* out_h   = out_txt + (size_t)N_ITEMS * DD;

    // -------- CSR workspace (after float region) --------
    float* eval_adj = f_end;
    float* eval_img = eval_adj + NNZ_ADJ;
    float* eval_txt = eval_img + NNZ_MM;
    int*   ecol_adj = (int*)(eval_txt + NNZ_MM);
    int*   ecol_img = ecol_adj + NNZ_ADJ;
    int*   ecol_txt = ecol_img + NNZ_MM;
    int*   cnt_adj  = ecol_txt + NNZ_MM;    // cnt arrays contiguous (one memset)
    int*   cnt_img  = cnt_adj + N_TOTAL;
    int*   cnt_txt  = cnt_img + N_ITEMS;
    int*   rp_adj   = cnt_txt + N_ITEMS;
    int*   rp_img   = rp_adj + N_TOTAL + 1;
    int*   rp_txt   = rp_img + N_ITEMS + 1;
    int*   off_adj  = rp_txt + N_ITEMS + 1;
    int*   off_img  = off_adj + N_TOTAL;
    int*   off_txt  = off_img + N_ITEMS;
    int*   i_end    = off_txt + N_ITEMS;

    const size_t CSR_NEED = (size_t)((char*)i_end - (char*)d_ws);
    const size_t AT_NEED  = (size_t)((char*)f_end - (char*)d_ws);

    if (ws_size >= CSR_NEED) {
        // ---- fast path: on-device CSR, no float atomics ----
        hipMemsetAsync(cnt_adj, 0, (size_t)(N_TOTAL + 2 * N_ITEMS) * sizeof(int), stream);

        k_count<<<1024, 256, 0, stream>>>(adj_rows, cnt_adj, NNZ_ADJ, N_TOTAL);
        k_count<<<512, 256, 0, stream>>>(img_rows, cnt_img, NNZ_MM, N_ITEMS);
        k_count<<<512, 256, 0, stream>>>(txt_rows, cnt_txt, NNZ_MM, N_ITEMS);

        ScanArg sa{cnt_adj, rp_adj, off_adj, N_TOTAL};
        ScanArg si{cnt_img, rp_img, off_img, N_ITEMS};
        ScanArg st{cnt_txt, rp_txt, off_txt, N_ITEMS};
        k_scan<<<3, 1024, 0, stream>>>(sa, si, st);

        k_scatter<<<1024, 256, 0, stream>>>(adj_rows, adj_cols, adj_vals, off_adj,
                                            ecol_adj, eval_adj, NNZ_ADJ, N_TOTAL, N_TOTAL);
        k_scatter<<<512, 256, 0, stream>>>(img_rows, img_cols, img_vals, off_img,
                                           ecol_img, eval_img, NNZ_MM, N_ITEMS, N_ITEMS);
        k_scatter<<<512, 256, 0, stream>>>(txt_rows, txt_cols, txt_vals, off_txt,
                                           ecol_txt, eval_txt, NNZ_MM, N_ITEMS, N_ITEMS);

        // modality SpMMs
        k_spmm_csr<<<(N_ITEMS + 3) / 4, 256, 0, stream>>>(rp_img, ecol_img, eval_img,
                                                          item_emb, img_e, N_ITEMS);
        k_spmm_csr<<<(N_ITEMS + 3) / 4, 256, 0, stream>>>(rp_txt, ecol_txt, eval_txt,
                                                          item_emb, txt_e, N_ITEMS);

        // UI propagation: cur1 = A*ego ; cur2 = A*cur1
        k_spmm_csr_ego<<<(N_TOTAL + 3) / 4, 256, 0, stream>>>(rp_adj, ecol_adj, eval_adj,
                                                              user_emb, item_emb, cur1, N_TOTAL);
        k_spmm_csr<<<(N_TOTAL + 3) / 4, 256, 0, stream>>>(rp_adj, ecol_adj, eval_adj,
                                                          cur1, cur2, N_TOTAL);
    } else if (ws_size >= AT_NEED) {
        // ---- fallback: atomic scatter path (round-5 proven) ----
        const size_t zero_floats = (size_t)N_ITEMS * DD * 2 + (size_t)N_TOTAL * DD * 2;
        hipMemsetAsync(d_ws, 0, zero_floats * sizeof(float), stream);
        k_spmm_at<<<1024, 256, 0, stream>>>(img_rows, img_cols, img_vals, item_emb,
                                            img_e, NNZ_MM, N_ITEMS, N_ITEMS);
        k_spmm_at<<<1024, 256, 0, stream>>>(txt_rows, txt_cols, txt_vals, item_emb,
                                            txt_e, NNZ_MM, N_ITEMS, N_ITEMS);
        k_spmm_at_ego<<<4096, 256, 0, stream>>>(adj_rows, adj_cols, adj_vals,
                                                user_emb, item_emb, cur1, NNZ_ADJ);
        k_spmm_at<<<4096, 256, 0, stream>>>(adj_rows, adj_cols, adj_vals, cur1,
                                            cur2, NNZ_ADJ, N_TOTAL, N_TOTAL);
    } else {
        k_sentinel<<<1, 64, 0, stream>>>(out, 3000.0f + (float)(ws_size >> 20));
        return;
    }

    // modality attention + h
    k_mm_fuse<<<512, 256, 0, stream>>>(img_e, txt_e, Wq1, bq1, wq2,
                                       h_ws, out_img, out_txt, out_h);

    // final outputs
    k_user_final<<<4096, 256, 0, stream>>>(user_emb, cur1, cur2, out_ug);
    k_item_final<<<512, 256, 0, stream>>>(item_emb, cur1, cur2, h_ws,
                                          Wc1, bc1, wc2, out_ig);
}

// Round 7
// 902.682 us; speedup vs baseline: 1.4417x; 1.0340x over previous
//
#include <hip/hip_runtime.h>

#define N_USERS 80000
#define N_ITEMS 30000
#define N_TOTAL 110000
#define DD 64
#define NNZ_ADJ 2000000
#define NNZ_MM 300000

// ---------------- diagnostic sentinel ---------------------------------------

__global__ void k_sentinel(float* out, float v)
{
    if (threadIdx.x == 0 && blockIdx.x == 0) out[0] = v;
}

// ======================= CSR construction ===================================

__global__ void k_count_all(const int* __restrict__ ar, const int* __restrict__ ir,
                            const int* __restrict__ tr,
                            int* __restrict__ ca, int* __restrict__ ci, int* __restrict__ ct)
{
    const int total = NNZ_ADJ + 2 * NNZ_MM;
    for (int i = blockIdx.x * blockDim.x + threadIdx.x; i < total;
         i += gridDim.x * blockDim.x) {
        int r, lim; int* c;
        if (i < NNZ_ADJ)               { r = ar[i];                     c = ca; lim = N_TOTAL; }
        else if (i < NNZ_ADJ + NNZ_MM) { r = ir[i - NNZ_ADJ];           c = ci; lim = N_ITEMS; }
        else                           { r = tr[i - NNZ_ADJ - NNZ_MM];  c = ct; lim = N_ITEMS; }
        if ((unsigned)r < (unsigned)lim) atomicAdd(c + r, 1);
    }
}

struct ScanArg { const int4* cnt; int* rp; int* off; int n; };

// 3 blocks, one per matrix; 8 elems/thread via int4; n must be divisible by 8.
__global__ __launch_bounds__(1024) void k_scan(ScanArg a0, ScanArg a1, ScanArg a2)
{
    ScanArg A = (blockIdx.x == 0) ? a0 : (blockIdx.x == 1) ? a1 : a2;
    __shared__ int swav[16];
    __shared__ int carry;
    const int lane = threadIdx.x & 63;
    const int wid  = threadIdx.x >> 6;
    if (threadIdx.x == 0) carry = 0;
    __syncthreads();

    for (int base = 0; base < A.n; base += 8192) {
        const int i0 = base + threadIdx.x * 8;
        int4 va = make_int4(0, 0, 0, 0), vb = make_int4(0, 0, 0, 0);
        if (i0 < A.n) { va = A.cnt[i0 >> 2]; vb = A.cnt[(i0 >> 2) + 1]; }
        const int tsum = va.x + va.y + va.z + va.w + vb.x + vb.y + vb.z + vb.w;

        int x = tsum;
        #pragma unroll
        for (int o = 1; o < 64; o <<= 1) {
            int t = __shfl_up(x, o);
            if (lane >= o) x += t;
        }
        if (lane == 63) swav[wid] = x;
        __syncthreads();
        if (wid == 0) {
            int y = (lane < 16) ? swav[lane] : 0;
            #pragma unroll
            for (int o = 1; o < 16; o <<= 1) {
                int t = __shfl_up(y, o);
                if (lane >= o) y += t;
            }
            if (lane < 16) swav[lane] = y;
        }
        __syncthreads();
        const int wbase = (wid > 0) ? swav[wid - 1] : 0;
        int e = carry + wbase + (x - tsum);

        int4 pa, pb;
        pa.x = e;            pa.y = pa.x + va.x;  pa.z = pa.y + va.y;  pa.w = pa.z + va.z;
        pb.x = pa.w + va.w;  pb.y = pb.x + vb.x;  pb.z = pb.y + vb.y;  pb.w = pb.z + vb.z;
        if (i0 < A.n) {
            ((int4*)A.rp)[i0 >> 2]        = pa;
            ((int4*)A.rp)[(i0 >> 2) + 1]  = pb;
            ((int4*)A.off)[i0 >> 2]       = pa;
            ((int4*)A.off)[(i0 >> 2) + 1] = pb;
        }
        const int tot = swav[15];
        __syncthreads();
        if (threadIdx.x == 0) carry += tot;
        __syncthreads();
    }
    if (threadIdx.x == 0) A.rp[A.n] = carry;
}

__global__ void k_scatter_all(
    const int* __restrict__ ar, const int* __restrict__ ac, const float* __restrict__ av,
    const int* __restrict__ ir, const int* __restrict__ ic, const float* __restrict__ iv,
    const int* __restrict__ tr, const int* __restrict__ tc, const float* __restrict__ tv,
    int* __restrict__ oa, int* __restrict__ oi, int* __restrict__ ot,
    int2* __restrict__ ea, int2* __restrict__ ei, int2* __restrict__ et)
{
    const int total = NNZ_ADJ + 2 * NNZ_MM;
    for (int i = blockIdx.x * blockDim.x + threadIdx.x; i < total;
         i += gridDim.x * blockDim.x) {
        int r, c, lim; float v; int* off; int2* ep;
        if (i < NNZ_ADJ) {
            r = ar[i]; c = ac[i]; v = av[i]; off = oa; ep = ea; lim = N_TOTAL;
        } else if (i < NNZ_ADJ + NNZ_MM) {
            const int j = i - NNZ_ADJ;
            r = ir[j]; c = ic[j]; v = iv[j]; off = oi; ep = ei; lim = N_ITEMS;
        } else {
            const int j = i - NNZ_ADJ - NNZ_MM;
            r = tr[j]; c = tc[j]; v = tv[j]; off = ot; ep = et; lim = N_ITEMS;
        }
        if ((unsigned)r >= (unsigned)lim || (unsigned)c >= (unsigned)lim) continue;
        const int pos = atomicAdd(&off[r], 1);
        ep[pos] = make_int2(c, __float_as_int(v));   // single 8B store
    }
}

// ======================= CSR SpMM core ======================================

__device__ __forceinline__ float csr_row(const int* __restrict__ rp,
                                         const int2* __restrict__ ep,
                                         const float* __restrict__ xb, // x + lane
                                         int r, int lane)
{
    const int j0 = rp[r], j1 = rp[r + 1];
    float acc = 0.f;
    for (int j = j0; j < j1; j += 64) {
        const int cnt = min(64, j1 - j);
        int2 e = make_int2(0, 0);
        if (lane < cnt) e = ep[j + lane];
        for (int k = 0; k < cnt; ++k) {
            const int   ck = __shfl(e.x, k);
            const float vk = __int_as_float(__shfl(e.y, k));
            acc += vk * xb[(size_t)ck * DD];
        }
    }
    return acc;
}

// modality SpMMs: rows [0, 2*N_ITEMS), img then txt, write straight to out
__global__ __launch_bounds__(256) void k_spmm_mm(
    const int* __restrict__ rp_i, const int2* __restrict__ ep_i,
    const int* __restrict__ rp_t, const int2* __restrict__ ep_t,
    const float* __restrict__ item_emb,
    float* __restrict__ out_img, float* __restrict__ out_txt)
{
    const int lane = threadIdx.x & 63;
    int wave       = blockIdx.x * (blockDim.x >> 6) + (threadIdx.x >> 6);
    const int nwav = gridDim.x * (blockDim.x >> 6);
    const float* xb = item_emb + lane;
    for (int r = wave; r < 2 * N_ITEMS; r += nwav) {
        if (r < N_ITEMS) {
            out_img[(size_t)r * DD + lane] = csr_row(rp_i, ep_i, xb, r, lane);
        } else {
            const int rr = r - N_ITEMS;
            out_txt[(size_t)rr * DD + lane] = csr_row(rp_t, ep_t, xb, rr, lane);
        }
    }
}

// cur1 = A * ego
__global__ __launch_bounds__(256) void k_spmm_ego(
    const int* __restrict__ rp, const int2* __restrict__ ep,
    const float* __restrict__ ue, const float* __restrict__ ie,
    float* __restrict__ out)
{
    const int lane = threadIdx.x & 63;
    int wave       = blockIdx.x * (blockDim.x >> 6) + (threadIdx.x >> 6);
    const int nwav = gridDim.x * (blockDim.x >> 6);
    const float* ub = ue + lane;
    const float* ib = ie + lane;
    for (int r = wave; r < N_TOTAL; r += nwav) {
        const int j0 = rp[r], j1 = rp[r + 1];
        float acc = 0.f;
        for (int j = j0; j < j1; j += 64) {
            const int cnt = min(64, j1 - j);
            int2 e = make_int2(0, 0);
            if (lane < cnt) e = ep[j + lane];
            for (int k = 0; k < cnt; ++k) {
                const int   ck = __shfl(e.x, k);
                const float vk = __int_as_float(__shfl(e.y, k));
                const float xv = (ck < N_USERS) ? ub[(size_t)ck * DD]
                                                : ib[(size_t)(ck - N_USERS) * DD];
                acc += vk * xv;
            }
        }
        out[(size_t)r * DD + lane] = acc;
    }
}

// -------- modality attention: reads out_img/out_txt, writes out_h only ------

__global__ __launch_bounds__(256) void k_mm_fuse(
    const float* __restrict__ img_e, const float* __restrict__ txt_e,
    const float* __restrict__ Wq1, const float* __restrict__ bq1, const float* __restrict__ wq2,
    float* __restrict__ out_h)
{
    __shared__ float sW[DD * DD];
    __shared__ float sb[DD];
    __shared__ float sq[DD];
    for (int i = threadIdx.x; i < DD * DD; i += blockDim.x) sW[i] = Wq1[i];
    if (threadIdx.x < DD) {
        sb[threadIdx.x] = bq1[threadIdx.x];
        sq[threadIdx.x] = wq2[threadIdx.x];
    }
    __syncthreads();

    const int lane = threadIdx.x & 63;
    int wave       = blockIdx.x * (blockDim.x >> 6) + (threadIdx.x >> 6);
    const int nwav = gridDim.x * (blockDim.x >> 6);

    for (int i = wave; i < N_ITEMS; i += nwav) {
        const size_t base = (size_t)i * DD + lane;
        const float iv = img_e[base];
        const float tv = txt_e[base];
        float ai = sb[lane], at = sb[lane];
        #pragma unroll 8
        for (int k = 0; k < DD; ++k) {
            const float w = sW[k * DD + lane];
            ai += __shfl(iv, k) * w;
            at += __shfl(tv, k) * w;
        }
        float si = tanhf(ai) * sq[lane];
        float st = tanhf(at) * sq[lane];
        #pragma unroll
        for (int off = 32; off; off >>= 1) {
            si += __shfl_xor(si, off);
            st += __shfl_xor(st, off);
        }
        const float m  = fmaxf(si, st);
        const float ei = expf(si - m), et = expf(st - m);
        out_h[base] = (ei * iv + et * tv) / (ei + et);
    }
}

// -------- fused final: cur2 row in registers + user/item epilogues ----------

__global__ __launch_bounds__(256) void k_final(
    const int* __restrict__ rp, const int2* __restrict__ ep,
    const float* __restrict__ cur1,
    const float* __restrict__ ue, const float* __restrict__ ie,
    const float* __restrict__ h_buf,
    const float* __restrict__ Wc1, const float* __restrict__ bc1, const float* __restrict__ wc2,
    float* __restrict__ out_ug, float* __restrict__ out_ig)
{
    __shared__ float sW[DD * DD];
    __shared__ float sb[DD];
    __shared__ float sq[DD];
    for (int i = threadIdx.x; i < DD * DD; i += blockDim.x) sW[i] = Wc1[i];
    if (threadIdx.x < DD) {
        sb[threadIdx.x] = bc1[threadIdx.x];
        sq[threadIdx.x] = wc2[threadIdx.x];
    }
    __syncthreads();

    const int lane = threadIdx.x & 63;
    int wave       = blockIdx.x * (blockDim.x >> 6) + (threadIdx.x >> 6);
    const int nwav = gridDim.x * (blockDim.x >> 6);
    const float* cb = cur1 + lane;

    for (int r = wave; r < N_TOTAL; r += nwav) {
        // acc = cur2 row r (A * cur1)
        const float acc = csr_row(rp, ep, cb, r, lane);
        const size_t gbase = (size_t)r * DD + lane;

        if (r < N_USERS) {
            out_ug[gbase] = (ue[gbase] + cur1[gbase] + acc) * (1.0f / 3.0f);
        } else {
            const int i = r - N_USERS;
            const size_t base = (size_t)i * DD + lane;
            const float ig = (ie[base] + cur1[gbase] + acc) * (1.0f / 3.0f);
            const float hv = h_buf[base];
            float ss = hv * hv;
            #pragma unroll
            for (int off = 32; off; off >>= 1) ss += __shfl_xor(ss, off);
            const float hn = hv / fmaxf(sqrtf(ss), 1e-12f);

            float a0 = sb[lane], a1 = sb[lane];
            #pragma unroll 8
            for (int k = 0; k < DD; ++k) {
                const float w = sW[k * DD + lane];
                a0 += __shfl(ig, k) * w;
                a1 += __shfl(hn, k) * w;
            }
            float s0 = tanhf(a0) * sq[lane];
            float s1 = tanhf(a1) * sq[lane];
            #pragma unroll
            for (int off = 32; off; off >>= 1) {
                s0 += __shfl_xor(s0, off);
                s1 += __shfl_xor(s1, off);
            }
            const float m  = fmaxf(s0, s1);
            const float e0 = expf(s0 - m), e1 = expf(s1 - m);
            out_ig[base] = (e0 * ig + e1 * hn) / (e0 + e1);
        }
    }
}

// ----------------------------------------------------------------------------

extern "C" void kernel_launch(void* const* d_in, const int* in_sizes, int n_in,
                              void* d_out, int out_size, void* d_ws, size_t ws_size,
                              hipStream_t stream)
{
    static const int EXP[17] = {
        N_USERS * DD, N_ITEMS * DD, DD * DD, DD, DD, DD * DD, DD, DD,
        NNZ_ADJ, NNZ_MM, NNZ_MM, NNZ_ADJ, NNZ_ADJ, NNZ_MM, NNZ_MM, NNZ_MM, NNZ_MM
    };

    float* out = (float*)d_out;

    const int OUT_EXPECT = (N_USERS + 4 * N_ITEMS) * DD;
    if (out_size != OUT_EXPECT) {
        k_sentinel<<<1, 64, 0, stream>>>(out, 5000.0f + (float)(((unsigned)out_size) >> 20));
        return;
    }
    if (n_in < 17) {
        k_sentinel<<<1, 64, 0, stream>>>(out, 1000.0f + 8.0f * (float)n_in);
        return;
    }

    int map[17];
    bool exact = true;
    for (int i = 0; i < 17; ++i) { map[i] = i; if (in_sizes[i] != EXP[i]) exact = false; }
    if (!exact) {
        bool used[64] = {false};
        for (int i = 0; i < 17; ++i) {
            int found = -1;
            for (int j = 0; j < n_in && j < 64; ++j)
                if (!used[j] && in_sizes[j] == EXP[i]) { found = j; break; }
            if (found < 0) {
                k_sentinel<<<1, 64, 0, stream>>>(out, 2000.0f + 32.0f * (float)i);
                return;
            }
            used[found] = true; map[i] = found;
        }
    }

    const float* user_emb = (const float*)d_in[map[0]];
    const float* item_emb = (const float*)d_in[map[1]];
    const float* Wq1      = (const float*)d_in[map[2]];
    const float* bq1      = (const float*)d_in[map[3]];
    const float* wq2      = (const float*)d_in[map[4]];
    const float* Wc1      = (const float*)d_in[map[5]];
    const float* bc1      = (const float*)d_in[map[6]];
    const float* wc2      = (const float*)d_in[map[7]];
    const float* adj_vals = (const float*)d_in[map[8]];
    const float* img_vals = (const float*)d_in[map[9]];
    const float* txt_vals = (const float*)d_in[map[10]];
    const int* adj_rows   = (const int*)d_in[map[11]];
    const int* adj_cols   = (const int*)d_in[map[12]];
    const int* img_rows   = (const int*)d_in[map[13]];
    const int* img_cols   = (const int*)d_in[map[14]];
    const int* txt_rows   = (const int*)d_in[map[15]];
    const int* txt_cols   = (const int*)d_in[map[16]];

    // -------- workspace layout (all 16B-aligned sections) --------
    float* cur1   = (float*)d_ws;                     // N_TOTAL*DD
    int2*  ep_adj = (int2*)(cur1 + (size_t)N_TOTAL * DD);
    int2*  ep_img = ep_adj + NNZ_ADJ;
    int2*  ep_txt = ep_img + NNZ_MM;
    int*   cnt_adj = (int*)(ep_txt + NNZ_MM);         // contiguous cnt block
    int*   cnt_img = cnt_adj + N_TOTAL;
    int*   cnt_txt = cnt_img + N_ITEMS;
    int*   rp_adj  = cnt_txt + N_ITEMS;               // padded to keep 16B align
    int*   rp_img  = rp_adj + 110004;
    int*   rp_txt  = rp_img + 30004;
    int*   off_adj = rp_txt + 30004;
    int*   off_img = off_adj + N_TOTAL;
    int*   off_txt = off_img + N_ITEMS;
    int*   i_end   = off_txt + N_ITEMS;

    const size_t WS_NEED = (size_t)((char*)i_end - (char*)d_ws);
    if (ws_size < WS_NEED) {
        k_sentinel<<<1, 64, 0, stream>>>(out, 3000.0f + (float)(ws_size >> 20));
        return;
    }

    float* out_ug  = out;
    float* out_ig  = out_ug  + (size_t)N_USERS * DD;
    float* out_img = out_ig  + (size_t)N_ITEMS * DD;
    float* out_txt = out_img + (size_t)N_ITEMS * DD;
    float* out_h   = out_txt + (size_t)N_ITEMS * DD;

    // ---- CSR build ----
    hipMemsetAsync(cnt_adj, 0, (size_t)(N_TOTAL + 2 * N_ITEMS) * sizeof(int), stream);
    k_count_all<<<2048, 256, 0, stream>>>(adj_rows, img_rows, txt_rows,
                                          cnt_adj, cnt_img, cnt_txt);

    ScanArg sa{(const int4*)cnt_adj, rp_adj, off_adj, N_TOTAL};
    ScanArg si{(const int4*)cnt_img, rp_img, off_img, N_ITEMS};
    ScanArg st{(const int4*)cnt_txt, rp_txt, off_txt, N_ITEMS};
    k_scan<<<3, 1024, 0, stream>>>(sa, si, st);

    k_scatter_all<<<2048, 256, 0, stream>>>(adj_rows, adj_cols, adj_vals,
                                            img_rows, img_cols, img_vals,
                                            txt_rows, txt_cols, txt_vals,
                                            off_adj, off_img, off_txt,
                                            ep_adj, ep_img, ep_txt);

    // ---- modality SpMM -> out_img/out_txt directly ----
    k_spmm_mm<<<15000, 256, 0, stream>>>(rp_img, ep_img, rp_txt, ep_txt,
                                         item_emb, out_img, out_txt);

    // ---- cur1 = A * ego ----
    k_spmm_ego<<<27500, 256, 0, stream>>>(rp_adj, ep_adj, user_emb, item_emb, cur1);

    // ---- modality attention -> out_h ----
    k_mm_fuse<<<512, 256, 0, stream>>>(out_img, out_txt, Wq1, bq1, wq2, out_h);

    // ---- fused: cur2 (in registers) + user/item epilogues ----
    k_final<<<2048, 256, 0, stream>>>(rp_adj, ep_adj, cur1, user_emb, item_emb,
                                      out_h, Wc1, bc1, wc2, out_ug, out_ig);
}